// Round 1
// 540.176 us; speedup vs baseline: 1.0230x; 1.0230x over previous
//
#include <hip/hip_runtime.h>

#define D_DIM   128
#define S_GRP   128
#define MARGINF 2.0f
#define KMARG   0.02f
#define EPSF    1e-6f

// ---------------------------------------------------------------------------
// 128-thread (2-wave) block sum reduction, result broadcast to all threads.
// ---------------------------------------------------------------------------
__device__ __forceinline__ float block_reduce_128(float x, volatile float* sh)
{
    #pragma unroll
    for (int off = 32; off; off >>= 1) x += __shfl_xor(x, off);
    __syncthreads();                       // protect sh from previous use
    if ((threadIdx.x & 63) == 0) sh[threadIdx.x >> 6] = x;
    __syncthreads();
    return sh[0] + sh[1];
}

// ---------------------------------------------------------------------------
// Fused kernel: block g owns group g (128 contiguous rows).
// Phase 1: each wave streams a 64-row slab of zr/zv with an explicit 2-deep
//          register double-buffer (8 dwordx4 loads in flight while the other
//          buffer's dot+reduce runs). R2 theory: VGPR_Count=44 proved the old
//          16-load batch was rolled by regalloc -> ~1 load in flight -> 3.3
//          TB/s effective. Named A/B buffers + full unroll + launch_bounds
//          (128,4) (cap ~128 VGPR) restore MLP.
// Phase 2: unchanged group losses + label-masked sums (labels moved out of
//          the hot loop; sumP/cntP derived exactly from group totals).
// ---------------------------------------------------------------------------
template <bool USE_PARTIALS>
__global__ __launch_bounds__(128, 4) void fused_kernel(
    const float* __restrict__ zr, const float* __restrict__ zv,
    const int* __restrict__ labels, const int* __restrict__ var_lens,
    float* __restrict__ dout,
    float* __restrict__ gl, float* __restrict__ pB, float* __restrict__ pP,
    float* __restrict__ pcB, float* __restrict__ pcP,
    double* __restrict__ wsd, int* __restrict__ wsi)
{
    const int g    = blockIdx.x;
    const int t    = threadIdx.x;
    const int w    = t >> 6;        // wave id 0/1
    const int lane = t & 63;
    const int half = lane >> 5;     // row sub-block within a step
    const int sub  = lane & 31;     // float4 slot within a row

    __shared__ __align__(16) float sv[S_GRP], sd[S_GRP], svs[S_GRP], sds[S_GRP];
    __shared__ float sred[2];

    // ---- phase 1: dot products for this wave's 64-row slab ----
    // step ls (0..7) covers rows slabRow + 8*ls .. +7 ; lanes 0-31 handle
    // rows +0..3 (u index), lanes 32-63 rows +4..7. 1 KB per load instr.
    const int slabRow = g * S_GRP + w * 64;
    const int ldsRow  = w * 64;

    float4 XA[4], YA[4], XB[4], YB[4];

#define LOAD8(X, Y, ls) do {                                                  \
        const float* _bz = zr + (size_t)(slabRow + 8*(ls) + 4*half) * D_DIM;  \
        const float* _bv = zv + (size_t)(slabRow + 8*(ls) + 4*half) * D_DIM;  \
        _Pragma("unroll")                                                     \
        for (int u = 0; u < 4; ++u) {                                         \
            X[u] = ((const float4*)(_bz + (size_t)u * D_DIM))[sub];           \
            Y[u] = ((const float4*)(_bv + (size_t)u * D_DIM))[sub];           \
        } } while (0)

#define DOT_STORE(X, Y, ls) do {                                              \
        float _p[4];                                                          \
        _Pragma("unroll")                                                     \
        for (int u = 0; u < 4; ++u)                                           \
            _p[u] = X[u].x*Y[u].x + X[u].y*Y[u].y                             \
                  + X[u].z*Y[u].z + X[u].w*Y[u].w;                            \
        _Pragma("unroll")                                                     \
        for (int off = 16; off; off >>= 1) {                                  \
            _Pragma("unroll")                                                 \
            for (int u = 0; u < 4; ++u) _p[u] += __shfl_xor(_p[u], off);      \
        }                                                                     \
        if (sub == 0) {                                                       \
            const float4 _dv = make_float4(1.f - _p[0], 1.f - _p[1],          \
                                           1.f - _p[2], 1.f - _p[3]);         \
            /* dout = out+2 is only 8B-aligned: two float2 stores */          \
            float* _dp = dout + (size_t)(slabRow + 8*(ls)) + 4*half;          \
            ((float2*)_dp)[0] = make_float2(_dv.x, _dv.y);                    \
            ((float2*)_dp)[1] = make_float2(_dv.z, _dv.w);                    \
            ((float4*)sd)[((ldsRow + 8*(ls)) >> 2) + half] = _dv;             \
        } } while (0)

    // fully unrolled 8-step, 2-deep software pipeline
    LOAD8(XA, YA, 0);
    LOAD8(XB, YB, 1);
    DOT_STORE(XA, YA, 0);
    LOAD8(XA, YA, 2);
    DOT_STORE(XB, YB, 1);
    LOAD8(XB, YB, 3);
    DOT_STORE(XA, YA, 2);
    LOAD8(XA, YA, 4);
    DOT_STORE(XB, YB, 3);
    LOAD8(XB, YB, 5);
    DOT_STORE(XA, YA, 4);
    LOAD8(XA, YA, 6);
    DOT_STORE(XB, YB, 5);
    LOAD8(XB, YB, 7);
    DOT_STORE(XA, YA, 6);
    DOT_STORE(XB, YB, 7);

#undef LOAD8
#undef DOT_STORE

    __syncthreads();   // sd[] complete for the whole group

    // ---- phase 2: per-group losses + label-masked sums ----
    const float v   = (float)var_lens[(size_t)g * S_GRP + t];
    const int   lab = labels[(size_t)g * S_GRP + t];
    const float d   = sd[t];
    sv[t] = v;

    const float mv = block_reduce_128(v, sred) * (1.0f / S_GRP);
    const float md = block_reduce_128(d, sred) * (1.0f / S_GRP);

    // labels in {0,1}: derive P-side exactly from totals (md*128 == total)
    const float sumB = block_reduce_128(lab == 0 ? d   : 0.f, sred);
    const float cntB = block_reduce_128(lab == 0 ? 1.f : 0.f, sred);
    const float sumP = md * (float)S_GRP - sumB;
    const float cntP = (float)S_GRP - cntB;

    const float cv = v - mv, cd = d - md;
    const float ssv = block_reduce_128(cv * cv, sred);
    const float ssd = block_reduce_128(cd * cd, sred);
    const float vs  = sqrtf(ssv * (1.0f / (S_GRP - 1)));
    const float dsd = sqrtf(ssd * (1.0f / (S_GRP - 1)));

    const float vz = cv / (vs + EPSF);
    const float dz = cd / (dsd + EPSF);
    const float df = vz - dz;
    float corr = block_reduce_128(df * df, sred) * (1.0f / S_GRP);
    if (!(vs > 0.f && dsd > 0.f)) corr = 0.f;

    // stable rank via counting (LDS broadcast reads — conflict-free)
    int rank = 0;
    #pragma unroll 8
    for (int j = 0; j < S_GRP; ++j) {
        const float vj = sv[j];
        rank += (vj < v) || (vj == v && j < t);
    }
    svs[rank] = v; sds[rank] = d;
    __syncthreads();

    float nv = 0.f;
    if (t < S_GRP - 1) nv = fmaxf(sds[t] - sds[t + 1] + KMARG, 0.f);
    const float neigh = block_reduce_128(nv, sred) * (1.0f / (S_GRP - 1));

    const float myv = svs[t], myd = sds[t];
    float viol = 0.f, cnt = 0.f;
    #pragma unroll 8
    for (int j = 0; j < S_GRP; ++j) {
        const float vj = svs[j];
        if (vj > myv) {
            cnt  += 1.f;
            viol += fmaxf(KMARG - (sds[j] - myd), 0.f);
        }
    }
    const float violT = block_reduce_128(viol, sred);
    const float cntT  = block_reduce_128(cnt,  sred);
    const float rloss = (cntT > 0.f) ? violT / cntT : 0.f;

    if (t == 0) {
        const float total = corr + neigh + rloss;
        if (USE_PARTIALS) {
            gl[g]  = total;
            pB[g]  = sumB; pP[g]  = sumP;
            pcB[g] = cntB; pcP[g] = cntP;
        } else {
            atomicAdd(&wsd[2], (double)total);
            atomicAdd(&wsd[0], (double)sumB);
            atomicAdd(&wsd[1], (double)sumP);
            atomicAdd(&wsi[0], (int)cntB);
            atomicAdd(&wsi[1], (int)cntP);
        }
    }
}

// ---------------------------------------------------------------------------
// Finalize (partials path): reduce per-group partials in one block.
// ---------------------------------------------------------------------------
__global__ __launch_bounds__(256) void finalize_kernel(
    const float* __restrict__ pB, const float* __restrict__ pP,
    const float* __restrict__ pcB, const float* __restrict__ pcP,
    const float* __restrict__ gl, float* __restrict__ out, int nGroups)
{
    double a0 = 0.0, a1 = 0.0, a2 = 0.0, a3 = 0.0, a4 = 0.0;
    for (int i = threadIdx.x; i < nGroups; i += 256) {
        a0 += (double)pB[i];
        a1 += (double)pP[i];
        a2 += (double)pcB[i];
        a3 += (double)pcP[i];
        a4 += (double)gl[i];
    }

    #pragma unroll
    for (int off = 32; off; off >>= 1) {
        a0 += __shfl_xor(a0, off);
        a1 += __shfl_xor(a1, off);
        a2 += __shfl_xor(a2, off);
        a3 += __shfl_xor(a3, off);
        a4 += __shfl_xor(a4, off);
    }
    __shared__ double red[5][4];
    const int w = threadIdx.x >> 6;
    if ((threadIdx.x & 63) == 0) {
        red[0][w] = a0; red[1][w] = a1; red[2][w] = a2; red[3][w] = a3; red[4][w] = a4;
    }
    __syncthreads();
    if (threadIdx.x == 0) {
        const double sB = red[0][0] + red[0][1] + red[0][2] + red[0][3];
        const double sP = red[1][0] + red[1][1] + red[1][2] + red[1][3];
        const double cB = red[2][0] + red[2][1] + red[2][2] + red[2][3];
        const double cP = red[3][0] + red[3][1] + red[3][2] + red[3][3];
        const double sG = red[4][0] + red[4][1] + red[4][2] + red[4][3];
        const double mean_b = sB / (cB > 0.0 ? cB : 1.0);
        const double mean_p = sP / (cP > 0.0 ? cP : 1.0);
        float l = 0.f;
        if (cB > 0.0 && cP > 0.0) {
            const double vv = (double)MARGINF + mean_b - mean_p;
            l = (float)(vv > 0.0 ? vv : 0.0);
        }
        out[0] = l;
        out[1] = (float)(sG / (double)nGroups);
    }
}

// ---------------------------------------------------------------------------
// Finalize (atomic fallback path): read 32-byte accumulator block.
// ---------------------------------------------------------------------------
__global__ void finalize_atomic_kernel(const double* __restrict__ wsd,
                                       const int* __restrict__ wsi,
                                       float* __restrict__ out, int nGroups)
{
    if (threadIdx.x == 0 && blockIdx.x == 0) {
        const int nb = wsi[0], np_ = wsi[1];
        const double mean_b = wsd[0] / (double)(nb  > 0 ? nb  : 1);
        const double mean_p = wsd[1] / (double)(np_ > 0 ? np_ : 1);
        float l = 0.f;
        if (nb > 0 && np_ > 0) {
            const double v = (double)MARGINF + mean_b - mean_p;
            l = (float)(v > 0.0 ? v : 0.0);
        }
        out[0] = l;
        out[1] = (float)(wsd[2] / (double)nGroups);
    }
}

extern "C" void kernel_launch(void* const* d_in, const int* in_sizes, int n_in,
                              void* d_out, int out_size, void* d_ws, size_t ws_size,
                              hipStream_t stream)
{
    const float* zr       = (const float*)d_in[0];
    const float* zv       = (const float*)d_in[1];
    const int*   labels   = (const int*)d_in[2];
    // d_in[3] = groups (arange//S, implied by contiguous layout) — unused
    const int*   var_lens = (const int*)d_in[4];
    float* out = (float*)d_out;

    const int N = in_sizes[2];      // labels length = N
    const int G = N / S_GRP;

    const size_t need = (size_t)G * 5 * sizeof(float);

    if (ws_size >= need) {
        // partials path — no global atomics, no memset
        float* pB  = (float*)d_ws;      // [G]
        float* pP  = pB  + G;           // [G]
        float* pcB = pP  + G;           // [G]
        float* pcP = pcB + G;           // [G]
        float* gl  = pcP + G;           // [G]

        fused_kernel<true><<<G, 128, 0, stream>>>(
            zr, zv, labels, var_lens, out + 2,
            gl, pB, pP, pcB, pcP, nullptr, nullptr);
        finalize_kernel<<<1, 256, 0, stream>>>(pB, pP, pcB, pcP, gl, out, G);
    } else {
        // 32-byte atomic fallback (R1-proven footprint)
        double* wsd = (double*)d_ws;                            // [3]
        int*    wsi = (int*)((char*)d_ws + 3 * sizeof(double)); // [2]
        hipMemsetAsync(d_ws, 0, 3 * sizeof(double) + 2 * sizeof(int), stream);

        fused_kernel<false><<<G, 128, 0, stream>>>(
            zr, zv, labels, var_lens, out + 2,
            nullptr, nullptr, nullptr, nullptr, nullptr, wsd, wsi);
        finalize_atomic_kernel<<<1, 64, 0, stream>>>(wsd, wsi, out, G);
    }
}